// Round 8
// baseline (177.525 us; speedup 1.0000x reference)
//
#include <hip/hip_runtime.h>
#include <math.h>

#define CH 64
#define SRV 8
#define HV 128
#define WV 128
#define NTOK (HV*WV)   // 16384
#define NKV 256        // pooled tokens (16x16)
#define POOLW 16
#define KVIMG 65536    // per-(branch,b) image: K' 32KB + V'T 32KB

// DIAGNOSTIC ROUND: attn launched 9x (idempotent) to decompose dur_us.
// attn_us = (dur_us - 8.8) / 9. Kernels themselves identical to round 7.
#define ATTN_REPS 9

typedef __attribute__((ext_vector_type(8))) short bf16x8;
typedef __attribute__((ext_vector_type(16))) float f32x16;

__device__ __forceinline__ unsigned short f2bf(float x) {
    unsigned u = __float_as_uint(x);
    return (unsigned short)((u + 0x7fffu + ((u >> 16) & 1u)) >> 16);  // RNE
}

__device__ __forceinline__ unsigned cvt_pk(float lo, float hi) {
    unsigned r;
    asm("v_cvt_pk_bf16_f32 %0, %1, %2" : "=v"(r) : "v"(lo), "v"(hi));
    return r;
}

// (oa,ob) = cross-half exchange. Verified on-HW (r6 pass).
__device__ __forceinline__ void plswap(unsigned a, unsigned b,
                                       unsigned &oa, unsigned &ob) {
#if __has_builtin(__builtin_amdgcn_permlane32_swap)
    auto r = __builtin_amdgcn_permlane32_swap(a, b, false, false);
    oa = r[0]; ob = r[1];
#else
    unsigned ax = (unsigned)__shfl_xor((int)a, 32);
    unsigned bx = (unsigned)__shfl_xor((int)b, 32);
    const bool lo = (threadIdx.x & 32) == 0;
    oa = lo ? a : bx;
    ob = lo ? ax : b;
#endif
}

__device__ __forceinline__ void gload_lds16(const void* g, void* l) {
    __builtin_amdgcn_global_load_lds(
        (const __attribute__((address_space(1))) void*)g,
        (__attribute__((address_space(3))) void*)l, 16, 0, 0);
}

// ---------------------------------------------------------------------------
// Kernel 1: 8x8 avg-pool -> LayerNorm -> kv proj -> fold weights ->
// write bf16 image: K'[key][k] swizzled, V'T[d][key] swizzled.
// 4 waves/block, one pooled token per wave. (r6-proven)
// ---------------------------------------------------------------------------
__global__ __launch_bounds__(256) void fused_pool_ln_kv(
    const float* __restrict__ x1, const float* __restrict__ x2,
    const float* __restrict__ kv1w, const float* __restrict__ kv2w,
    const float* __restrict__ n1g, const float* __restrict__ n1b,
    const float* __restrict__ n2g, const float* __restrict__ n2b,
    const float* __restrict__ q1w,
    const float* __restrict__ p1w, const float* __restrict__ p2w,
    char* __restrict__ kvbuf, int B)
{
    const int c  = threadIdx.x & 63;
    const int wv = threadIdx.x >> 6;
    const int g  = blockIdx.x * 4 + wv;    // global token id
    const int m = g % NKV;
    const int t = g / NKV;
    const int b = t % B;
    const int branch = t / B;

    const float* x   = branch ? x2   : x1;
    const float* kvw = branch ? kv2w : kv1w;
    const float* gg  = branch ? n2g  : n1g;
    const float* be  = branch ? n2b  : n1b;
    const float* pw  = branch ? p2w  : p1w;

    const int ph = m / POOLW, pwc = m % POOLW;
    const float* xb = x + ((size_t)b * NTOK) * CH;

    float sum = 0.f;
    for (int dy = 0; dy < SRV; ++dy) {
        const int y = ph * SRV + dy;
        const float* xr = xb + ((size_t)(y * WV + pwc * SRV)) * CH + c;
        #pragma unroll
        for (int dx = 0; dx < SRV; ++dx)
            sum += xr[dx * CH];
    }
    float v = sum * (1.f / 64.f);

    float mu = v;
    #pragma unroll
    for (int o = 32; o; o >>= 1) mu += __shfl_xor(mu, o);
    mu *= (1.f / 64.f);
    float d = v - mu;
    float var = d * d;
    #pragma unroll
    for (int o = 32; o; o >>= 1) var += __shfl_xor(var, o);
    var *= (1.f / 64.f);
    float xp = d * rsqrtf(var + 1e-5f) * gg[c] + be[c];

    __shared__ float sx[4][CH];
    __shared__ float kb[4][CH];
    __shared__ float vb[4][CH];
    sx[wv][c] = xp;
    __syncthreads();

    float ka = 0.f, va = 0.f;
    #pragma unroll
    for (int dd = 0; dd < CH; ++dd) {
        const float xd = sx[wv][dd];
        ka += xd * kvw[(size_t)c * CH + dd];
        va += xd * kvw[(size_t)(CH + c) * CH + dd];
    }
    kb[wv][c] = ka;
    vb[wv][c] = va;
    __syncthreads();

    // fold: k'[c] = 0.125 * sum_j k[j]*q1w[j,c] ; v'[c] = sum_j v[j]*pw[c,j]
    float k2 = 0.f, v2 = 0.f;
    #pragma unroll
    for (int j = 0; j < CH; ++j) {
        k2 += kb[wv][j] * q1w[(size_t)j * CH + c];
        v2 += vb[wv][j] * pw[(size_t)c * CH + j];
    }
    k2 *= 0.125f;

    char* base = kvbuf + (size_t)(branch * B + b) * KVIMG;
    *(unsigned short*)(base + m * 128 + ((2 * c) ^ ((m & 7) << 4))) = f2bf(k2);
    *(unsigned short*)(base + 32768 + c * 512 + ((2 * m) ^ ((c & 7) << 4))) = f2bf(v2);
}

// ---------------------------------------------------------------------------
// Kernel 2: MFMA attention (identical to round 7).
// 8 waves x 32 rows = 256 rows/block, grid 512, 2 blocks/CU.
// BUG HISTORY (r3-r5): x fragment load must honor layout kc*16 + hi*8.
// ---------------------------------------------------------------------------
__global__ __launch_bounds__(512, 4) void fused_attn_mfma(
    const float* __restrict__ x1, const float* __restrict__ x2,
    const char* __restrict__ kvbuf,
    const float* __restrict__ p1b, const float* __restrict__ p2b,
    float* __restrict__ out, int B)
{
    extern __shared__ char KV[];           // 64 KB: K image | V image
    const int tpg = NTOK / 256;            // 64 row-groups per (branch,b)
    const int blk = blockIdx.x;
    const int branch = blk / (B * tpg);
    const int rem = blk - branch * (B * tpg);
    const int b = rem / tpg;
    const int tg = rem - b * tpg;

    const float* x  = branch ? x2  : x1;
    const float* pb = branch ? p2b : p1b;
    const char* kvbase = kvbuf + (size_t)(branch * B + b) * KVIMG;

    const int tid = threadIdx.x;
    const int lane = tid & 63;
    const int wv = tid >> 6;               // 0..7
    const int l31 = lane & 31;
    const int hi = lane >> 5;
    const int hi16 = hi * 16, hi8 = hi * 8;
    const int swz = (l31 & 7) << 4;

    // stage 64 KB image: global -> LDS direct, 16B/lane x 64 lanes x 8 iter
    {
        #pragma unroll
        for (int i = 0; i < 8; ++i)
            gload_lds16(kvbase + i * 8192 + wv * 1024 + (lane << 4),
                        KV + i * 8192 + wv * 1024);
    }

    // load this wave's x row fragments (drains at the same barrier):
    // lane holds X[row][k = kc*16 + hi*8 + j]
    const int row = tg * 256 + wv * 32 + l31;
    float4 xq[8];
    {
        const float* xr = x + ((size_t)b * NTOK + row) * CH;
        #pragma unroll
        for (int kc = 0; kc < 4; ++kc) {
            xq[2 * kc]     = *(const float4*)(xr + kc * 16 + hi8);
            xq[2 * kc + 1] = *(const float4*)(xr + kc * 16 + hi8 + 4);
        }
    }
    __syncthreads();

    union U8 { bf16x8 v; unsigned d[4]; };

    // pack X^T B-fragments
    bf16x8 xf[4];
    #pragma unroll
    for (int kc = 0; kc < 4; ++kc) {
        const float4 a  = xq[2 * kc];
        const float4 c4 = xq[2 * kc + 1];
        U8 u;
        u.d[0] = cvt_pk(a.x, a.y);   u.d[1] = cvt_pk(a.z, a.w);
        u.d[2] = cvt_pk(c4.x, c4.y); u.d[3] = cvt_pk(c4.z, c4.w);
        xf[kc] = u.v;
    }

    f32x16 oac[2];
    #pragma unroll
    for (int df = 0; df < 2; ++df)
        #pragma unroll
        for (int r = 0; r < 16; ++r) oac[df][r] = 0.f;

    float lsum = 0.f;

    // 4 groups of 64 keys: QK -> exp -> pack -> PV
    #pragma unroll
    for (int kp = 0; kp < 4; ++kp) {
        f32x16 a0, a1;
        #pragma unroll
        for (int r = 0; r < 16; ++r) { a0[r] = 0.f; a1[r] = 0.f; }
        const int key0 = kp * 64 + l31;
        __builtin_amdgcn_s_setprio(1);
        #pragma unroll
        for (int kc = 0; kc < 4; ++kc) {
            const int co = (kc * 32 + hi16) ^ swz;
            const bf16x8 k0 = *(const bf16x8*)(KV + key0 * 128 + co);
            const bf16x8 k1 = *(const bf16x8*)(KV + (key0 + 32) * 128 + co);
            a0 = __builtin_amdgcn_mfma_f32_32x32x16_bf16(k0, xf[kc], a0, 0, 0, 0);
            a1 = __builtin_amdgcn_mfma_f32_32x32x16_bf16(k1, xf[kc], a1, 0, 0, 0);
        }
        __builtin_amdgcn_s_setprio(0);

        float p0[16], p1[16];
        #pragma unroll
        for (int r = 0; r < 16; ++r) {
            p0[r] = __expf(a0[r]); lsum += p0[r];
            p1[r] = __expf(a1[r]); lsum += p1[r];
        }
        bf16x8 pvB[4];
        #pragma unroll
        for (int h = 0; h < 2; ++h) {
            const float* p = h ? p1 : p0;
            unsigned q0, q1, q2, q3;
            U8 u;
            plswap(cvt_pk(p[0], p[1]), cvt_pk(p[4], p[5]), q0, q2);
            plswap(cvt_pk(p[2], p[3]), cvt_pk(p[6], p[7]), q1, q3);
            u.d[0] = q0; u.d[1] = q1; u.d[2] = q2; u.d[3] = q3;
            pvB[2 * h] = u.v;
            plswap(cvt_pk(p[8], p[9]),   cvt_pk(p[12], p[13]), q0, q2);
            plswap(cvt_pk(p[10], p[11]), cvt_pk(p[14], p[15]), q1, q3);
            u.d[0] = q0; u.d[1] = q1; u.d[2] = q2; u.d[3] = q3;
            pvB[2 * h + 1] = u.v;
        }

        // PV for this key group: t-chunks 4kp..4kp+3
        __builtin_amdgcn_s_setprio(1);
        #pragma unroll
        for (int tc = 0; tc < 4; ++tc) {
            const int t = 4 * kp + tc;
            const int co = (t * 32 + hi16) ^ swz;
            const bf16x8 vf0 = *(const bf16x8*)(KV + 32768 + l31 * 512 + co);
            const bf16x8 vf1 = *(const bf16x8*)(KV + 32768 + (32 + l31) * 512 + co);
            oac[0] = __builtin_amdgcn_mfma_f32_32x32x16_bf16(vf0, pvB[tc], oac[0], 0, 0, 0);
            oac[1] = __builtin_amdgcn_mfma_f32_32x32x16_bf16(vf1, pvB[tc], oac[1], 0, 0, 0);
        }
        __builtin_amdgcn_s_setprio(0);
    }

    const float lfull = lsum + __shfl_xor(lsum, 32);
    const float invl = 1.f / lfull;

    // epilogue: out[row][d] = O^T[d][row]/l + pb[d]
    float* orow = out + ((size_t)(branch * B + b) * NTOK + row) * CH;
    #pragma unroll
    for (int df = 0; df < 2; ++df) {
        #pragma unroll
        for (int q = 0; q < 4; ++q) {
            const int d0 = df * 32 + q * 8 + hi * 4;
            const float4 bias = *(const float4*)(pb + d0);
            float4 w;
            w.x = oac[df][4 * q + 0] * invl + bias.x;
            w.y = oac[df][4 * q + 1] * invl + bias.y;
            w.z = oac[df][4 * q + 2] * invl + bias.z;
            w.w = oac[df][4 * q + 3] * invl + bias.w;
            *(float4*)(orow + d0) = w;
        }
    }
}

extern "C" void kernel_launch(void* const* d_in, const int* in_sizes, int n_in,
                              void* d_out, int out_size, void* d_ws, size_t ws_size,
                              hipStream_t stream) {
    const float* x1   = (const float*)d_in[0];
    const float* x2   = (const float*)d_in[1];
    const float* q1w  = (const float*)d_in[4];
    const float* kv1w = (const float*)d_in[5];
    const float* kv2w = (const float*)d_in[6];
    const float* n1g  = (const float*)d_in[7];
    const float* n1b  = (const float*)d_in[8];
    const float* n2g  = (const float*)d_in[9];
    const float* n2b  = (const float*)d_in[10];
    const float* p1w  = (const float*)d_in[11];
    const float* p1b  = (const float*)d_in[12];
    const float* p2w  = (const float*)d_in[13];
    const float* p2b  = (const float*)d_in[14];

    const int B = in_sizes[0] / (NTOK * CH);
    char* kvbuf = (char*)d_ws;   // 2*B*64KB = 512 KB

    fused_pool_ln_kv<<<2 * B * NKV / 4, 256, 0, stream>>>(
        x1, x2, kv1w, kv2w, n1g, n1b, n2g, n2b, q1w, p1w, p2w, kvbuf, B);

    // DIAGNOSTIC: repeat attn (idempotent rewrites of d_out) to measure
    // its true per-launch cost: attn_us = (dur_us - 8.8) / ATTN_REPS.
    for (int rep = 0; rep < ATTN_REPS; ++rep)
        fused_attn_mfma<<<2 * B * (NTOK / 256), 512, KVIMG, stream>>>(
            x1, x2, kvbuf, p1b, p2b, (float*)d_out, B);
}

// Round 9
// 40.171 us; speedup vs baseline: 4.4192x; 4.4192x over previous
//
#include <hip/hip_runtime.h>
#include <math.h>

#define CH 64
#define SRV 8
#define HV 128
#define WV 128
#define NTOK (HV*WV)   // 16384
#define NKV 256        // pooled tokens (16x16)
#define POOLW 16
#define KVIMG 65536    // per-(branch,b) image: K' 32KB + V'T 32KB

typedef __attribute__((ext_vector_type(8))) short bf16x8;
typedef __attribute__((ext_vector_type(16))) float f32x16;

__device__ __forceinline__ unsigned short f2bf(float x) {
    unsigned u = __float_as_uint(x);
    return (unsigned short)((u + 0x7fffu + ((u >> 16) & 1u)) >> 16);  // RNE
}

__device__ __forceinline__ unsigned cvt_pk(float lo, float hi) {
    unsigned r;
    asm("v_cvt_pk_bf16_f32 %0, %1, %2" : "=v"(r) : "v"(lo), "v"(hi));
    return r;
}

// (oa,ob) = cross-half exchange. Verified on-HW (r6/r7 pass).
__device__ __forceinline__ void plswap(unsigned a, unsigned b,
                                       unsigned &oa, unsigned &ob) {
#if __has_builtin(__builtin_amdgcn_permlane32_swap)
    auto r = __builtin_amdgcn_permlane32_swap(a, b, false, false);
    oa = r[0]; ob = r[1];
#else
    unsigned ax = (unsigned)__shfl_xor((int)a, 32);
    unsigned bx = (unsigned)__shfl_xor((int)b, 32);
    const bool lo = (threadIdx.x & 32) == 0;
    oa = lo ? a : bx;
    ob = lo ? ax : b;
#endif
}

__device__ __forceinline__ void gload_lds16(const void* g, void* l) {
    __builtin_amdgcn_global_load_lds(
        (const __attribute__((address_space(1))) void*)g,
        (__attribute__((address_space(3))) void*)l, 16, 0, 0);
}

// ---------------------------------------------------------------------------
// Kernel 1: 8x8 avg-pool -> LayerNorm -> kv proj -> fold weights ->
// write bf16 image: K'[key][k] swizzled, V'T[d][key] swizzled.
// 4 waves/block, one pooled token per wave. (r6-proven)
// ---------------------------------------------------------------------------
__global__ __launch_bounds__(256) void fused_pool_ln_kv(
    const float* __restrict__ x1, const float* __restrict__ x2,
    const float* __restrict__ kv1w, const float* __restrict__ kv2w,
    const float* __restrict__ n1g, const float* __restrict__ n1b,
    const float* __restrict__ n2g, const float* __restrict__ n2b,
    const float* __restrict__ q1w,
    const float* __restrict__ p1w, const float* __restrict__ p2w,
    char* __restrict__ kvbuf, int B)
{
    const int c  = threadIdx.x & 63;
    const int wv = threadIdx.x >> 6;
    const int g  = blockIdx.x * 4 + wv;    // global token id
    const int m = g % NKV;
    const int t = g / NKV;
    const int b = t % B;
    const int branch = t / B;

    const float* x   = branch ? x2   : x1;
    const float* kvw = branch ? kv2w : kv1w;
    const float* gg  = branch ? n2g  : n1g;
    const float* be  = branch ? n2b  : n1b;
    const float* pw  = branch ? p2w  : p1w;

    const int ph = m / POOLW, pwc = m % POOLW;
    const float* xb = x + ((size_t)b * NTOK) * CH;

    float sum = 0.f;
    for (int dy = 0; dy < SRV; ++dy) {
        const int y = ph * SRV + dy;
        const float* xr = xb + ((size_t)(y * WV + pwc * SRV)) * CH + c;
        #pragma unroll
        for (int dx = 0; dx < SRV; ++dx)
            sum += xr[dx * CH];
    }
    float v = sum * (1.f / 64.f);

    float mu = v;
    #pragma unroll
    for (int o = 32; o; o >>= 1) mu += __shfl_xor(mu, o);
    mu *= (1.f / 64.f);
    float d = v - mu;
    float var = d * d;
    #pragma unroll
    for (int o = 32; o; o >>= 1) var += __shfl_xor(var, o);
    var *= (1.f / 64.f);
    float xp = d * rsqrtf(var + 1e-5f) * gg[c] + be[c];

    __shared__ float sx[4][CH];
    __shared__ float kb[4][CH];
    __shared__ float vb[4][CH];
    sx[wv][c] = xp;
    __syncthreads();

    float ka = 0.f, va = 0.f;
    #pragma unroll
    for (int dd = 0; dd < CH; ++dd) {
        const float xd = sx[wv][dd];
        ka += xd * kvw[(size_t)c * CH + dd];
        va += xd * kvw[(size_t)(CH + c) * CH + dd];
    }
    kb[wv][c] = ka;
    vb[wv][c] = va;
    __syncthreads();

    // fold: k'[c] = 0.125 * sum_j k[j]*q1w[j,c] ; v'[c] = sum_j v[j]*pw[c,j]
    float k2 = 0.f, v2 = 0.f;
    #pragma unroll
    for (int j = 0; j < CH; ++j) {
        k2 += kb[wv][j] * q1w[(size_t)j * CH + c];
        v2 += vb[wv][j] * pw[(size_t)c * CH + j];
    }
    k2 *= 0.125f;

    char* base = kvbuf + (size_t)(branch * B + b) * KVIMG;
    *(unsigned short*)(base + m * 128 + ((2 * c) ^ ((m & 7) << 4))) = f2bf(k2);
    *(unsigned short*)(base + 32768 + c * 512 + ((2 * m) ^ ((c & 7) << 4))) = f2bf(v2);
}

// ---------------------------------------------------------------------------
// Kernel 2: MFMA attention (r7-proven). 8 waves x 32 rows = 256 rows/block,
// grid 512, 2 blocks/CU. PV interleaved per 64-key group (4 P-chunks live).
// BUG HISTORY (r3-r5): x fragment load must honor layout kc*16 + hi*8.
// ---------------------------------------------------------------------------
__global__ __launch_bounds__(512, 4) void fused_attn_mfma(
    const float* __restrict__ x1, const float* __restrict__ x2,
    const char* __restrict__ kvbuf,
    const float* __restrict__ p1b, const float* __restrict__ p2b,
    float* __restrict__ out, int B)
{
    extern __shared__ char KV[];           // 64 KB: K image | V image
    const int tpg = NTOK / 256;            // 64 row-groups per (branch,b)
    const int blk = blockIdx.x;
    const int branch = blk / (B * tpg);
    const int rem = blk - branch * (B * tpg);
    const int b = rem / tpg;
    const int tg = rem - b * tpg;

    const float* x  = branch ? x2  : x1;
    const float* pb = branch ? p2b : p1b;
    const char* kvbase = kvbuf + (size_t)(branch * B + b) * KVIMG;

    const int tid = threadIdx.x;
    const int lane = tid & 63;
    const int wv = tid >> 6;               // 0..7
    const int l31 = lane & 31;
    const int hi = lane >> 5;
    const int hi16 = hi * 16, hi8 = hi * 8;
    const int swz = (l31 & 7) << 4;

    // stage 64 KB image: global -> LDS direct, 16B/lane x 64 lanes x 8 iter
    {
        #pragma unroll
        for (int i = 0; i < 8; ++i)
            gload_lds16(kvbase + i * 8192 + wv * 1024 + (lane << 4),
                        KV + i * 8192 + wv * 1024);
    }

    // load this wave's x row fragments (drains at the same barrier):
    // lane holds X[row][k = kc*16 + hi*8 + j]
    const int row = tg * 256 + wv * 32 + l31;
    float4 xq[8];
    {
        const float* xr = x + ((size_t)b * NTOK + row) * CH;
        #pragma unroll
        for (int kc = 0; kc < 4; ++kc) {
            xq[2 * kc]     = *(const float4*)(xr + kc * 16 + hi8);
            xq[2 * kc + 1] = *(const float4*)(xr + kc * 16 + hi8 + 4);
        }
    }
    __syncthreads();

    union U8 { bf16x8 v; unsigned d[4]; };

    // pack X^T B-fragments
    bf16x8 xf[4];
    #pragma unroll
    for (int kc = 0; kc < 4; ++kc) {
        const float4 a  = xq[2 * kc];
        const float4 c4 = xq[2 * kc + 1];
        U8 u;
        u.d[0] = cvt_pk(a.x, a.y);   u.d[1] = cvt_pk(a.z, a.w);
        u.d[2] = cvt_pk(c4.x, c4.y); u.d[3] = cvt_pk(c4.z, c4.w);
        xf[kc] = u.v;
    }

    f32x16 oac[2];
    #pragma unroll
    for (int df = 0; df < 2; ++df)
        #pragma unroll
        for (int r = 0; r < 16; ++r) oac[df][r] = 0.f;

    float lsum = 0.f;

    // 4 groups of 64 keys: QK -> exp -> pack -> PV
    #pragma unroll
    for (int kp = 0; kp < 4; ++kp) {
        f32x16 a0, a1;
        #pragma unroll
        for (int r = 0; r < 16; ++r) { a0[r] = 0.f; a1[r] = 0.f; }
        const int key0 = kp * 64 + l31;
        __builtin_amdgcn_s_setprio(1);
        #pragma unroll
        for (int kc = 0; kc < 4; ++kc) {
            const int co = (kc * 32 + hi16) ^ swz;
            const bf16x8 k0 = *(const bf16x8*)(KV + key0 * 128 + co);
            const bf16x8 k1 = *(const bf16x8*)(KV + (key0 + 32) * 128 + co);
            a0 = __builtin_amdgcn_mfma_f32_32x32x16_bf16(k0, xf[kc], a0, 0, 0, 0);
            a1 = __builtin_amdgcn_mfma_f32_32x32x16_bf16(k1, xf[kc], a1, 0, 0, 0);
        }
        __builtin_amdgcn_s_setprio(0);

        float p0[16], p1[16];
        #pragma unroll
        for (int r = 0; r < 16; ++r) {
            p0[r] = __expf(a0[r]); lsum += p0[r];
            p1[r] = __expf(a1[r]); lsum += p1[r];
        }
        bf16x8 pvB[4];
        #pragma unroll
        for (int h = 0; h < 2; ++h) {
            const float* p = h ? p1 : p0;
            unsigned q0, q1, q2, q3;
            U8 u;
            plswap(cvt_pk(p[0], p[1]), cvt_pk(p[4], p[5]), q0, q2);
            plswap(cvt_pk(p[2], p[3]), cvt_pk(p[6], p[7]), q1, q3);
            u.d[0] = q0; u.d[1] = q1; u.d[2] = q2; u.d[3] = q3;
            pvB[2 * h] = u.v;
            plswap(cvt_pk(p[8], p[9]),   cvt_pk(p[12], p[13]), q0, q2);
            plswap(cvt_pk(p[10], p[11]), cvt_pk(p[14], p[15]), q1, q3);
            u.d[0] = q0; u.d[1] = q1; u.d[2] = q2; u.d[3] = q3;
            pvB[2 * h + 1] = u.v;
        }

        // PV for this key group: t-chunks 4kp..4kp+3
        __builtin_amdgcn_s_setprio(1);
        #pragma unroll
        for (int tc = 0; tc < 4; ++tc) {
            const int t = 4 * kp + tc;
            const int co = (t * 32 + hi16) ^ swz;
            const bf16x8 vf0 = *(const bf16x8*)(KV + 32768 + l31 * 512 + co);
            const bf16x8 vf1 = *(const bf16x8*)(KV + 32768 + (32 + l31) * 512 + co);
            oac[0] = __builtin_amdgcn_mfma_f32_32x32x16_bf16(vf0, pvB[tc], oac[0], 0, 0, 0);
            oac[1] = __builtin_amdgcn_mfma_f32_32x32x16_bf16(vf1, pvB[tc], oac[1], 0, 0, 0);
        }
        __builtin_amdgcn_s_setprio(0);
    }

    const float lfull = lsum + __shfl_xor(lsum, 32);
    const float invl = 1.f / lfull;

    // epilogue: out[row][d] = O^T[d][row]/l + pb[d]
    float* orow = out + ((size_t)(branch * B + b) * NTOK + row) * CH;
    #pragma unroll
    for (int df = 0; df < 2; ++df) {
        #pragma unroll
        for (int q = 0; q < 4; ++q) {
            const int d0 = df * 32 + q * 8 + hi * 4;
            const float4 bias = *(const float4*)(pb + d0);
            float4 w;
            w.x = oac[df][4 * q + 0] * invl + bias.x;
            w.y = oac[df][4 * q + 1] * invl + bias.y;
            w.z = oac[df][4 * q + 2] * invl + bias.z;
            w.w = oac[df][4 * q + 3] * invl + bias.w;
            *(float4*)(orow + d0) = w;
        }
    }
}

extern "C" void kernel_launch(void* const* d_in, const int* in_sizes, int n_in,
                              void* d_out, int out_size, void* d_ws, size_t ws_size,
                              hipStream_t stream) {
    const float* x1   = (const float*)d_in[0];
    const float* x2   = (const float*)d_in[1];
    const float* q1w  = (const float*)d_in[4];
    const float* kv1w = (const float*)d_in[5];
    const float* kv2w = (const float*)d_in[6];
    const float* n1g  = (const float*)d_in[7];
    const float* n1b  = (const float*)d_in[8];
    const float* n2g  = (const float*)d_in[9];
    const float* n2b  = (const float*)d_in[10];
    const float* p1w  = (const float*)d_in[11];
    const float* p1b  = (const float*)d_in[12];
    const float* p2w  = (const float*)d_in[13];
    const float* p2b  = (const float*)d_in[14];

    const int B = in_sizes[0] / (NTOK * CH);
    char* kvbuf = (char*)d_ws;   // 2*B*64KB = 512 KB

    fused_pool_ln_kv<<<2 * B * NKV / 4, 256, 0, stream>>>(
        x1, x2, kv1w, kv2w, n1g, n1b, n2g, n2b, q1w, p1w, p2w, kvbuf, B);

    fused_attn_mfma<<<2 * B * (NTOK / 256), 512, KVIMG, stream>>>(
        x1, x2, kvbuf, p1b, p2b, (float*)d_out, B);
}